// Round 10
// baseline (7645.789 us; speedup 1.0000x reference)
//
#include <hip/hip_runtime.h>

#define NB 4
#define NPT 32768
#define QPT 8192          // points per quarter-cloud
#define CIN 128
#define COUT 256
#define NS 2048
#define THR 512
#define PPT 16            // points per thread (QPT / THR)

// ws float-offset layout
#define WS_G 0            // 128*128 Gram
#define WS_FSUM 16384     // 128 column sums
#define WS_SLOT 16512     // 4 clouds x 2 par x 32 wave-slots u64 = 512 floats
#define WS_GSCALE 17024   // 256
#define WS_GBIAS 17280    // 256
#define WS_IDX 17536      // 8192 ints

// d_out float-offset layout
#define OUT_COORD 0
#define OUT_FEAT 24576
#define OUT_OFFS 2121728

// Established rounds 1-9:
//  * Register cap follows LDS-derived occupancy ONLY (attributes ignored):
//    2.5 KB LDS -> cap ~64 (r8/r9: VGPR_Count 48-52 -> coords were NOT in
//    registers; compiler re-loaded px/py/pz from L2 every iteration = the
//    hidden ~1700 cyc/iter). 61-84 KB LDS -> cap 128.
//  * Fix: 64 KB static LDS -> 2 blocks/CU -> cap 128; the 16-pt/thread
//    state (48 coord + 16 dist + temps ~ 90) is then register-resident.
//  * WRITE_SIZE ~66 MB = Gram's memory-side atomics; expected, harmless.
//  * rocprof inflates spin-poll kernels; compare unprofiled totals.
//  * Sync: per-WAVE tagged slots (it<<48 | dbits<<15 | (32767-gidx), tag
//    makes stale values lose automatically). Wave butterfly-reduce -> lane0
//    stores its slot -> all waves poll all 32 slots (coalesced, __all tag
//    check) -> butterfly merge. NO __syncthreads in the FPS loop. Slot
//    reuse at parity distance 2 safe: store(it+2) happens-after passing
//    poll(it+1) which requires every wave consumed (it).
__global__ __launch_bounds__(THR) void fused1(
    const float* __restrict__ coord, const float* __restrict__ feat,
    float* __restrict__ wsf, int* __restrict__ wsi,
    unsigned long long* __restrict__ slots)
{
  __shared__ float smem[16384];   // 65536 B: forces 2 blocks/CU -> reg cap 128
  const int bid = blockIdx.x;
  const int t = threadIdx.x;
  const bool is_fps = (bid < 32) && ((bid & 7) < 4);

  if (is_fps) {
    // ---------------- FPS: cloud cl, quarter h ----------------
    const int cl = bid & 3;
    const int h = bid >> 3;                    // 0..3; %8 keeps them one XCD
    const int gbase = h * QPT;
    const float* xyz = coord + (size_t)cl * NPT * 3;
    int* idx_out = wsi + cl * NS;
    unsigned long long* slot = slots + cl * 64;   // [par][32]

    float px[PPT], py[PPT], pz[PPT], dv[PPT];
#pragma unroll
    for (int j = 0; j < PPT; ++j) {
      int p = gbase + j * THR + t;
      px[j] = xyz[p * 3 + 0];
      py[j] = xyz[p * 3 + 1];
      pz[j] = xyz[p * 3 + 2];
      dv[j] = 1e10f;
    }
    if (h == 0 && t == 0) idx_out[0] = 0;      // every cloud writes sample 0
    float cx = xyz[0], cy = xyz[1], cz = xyz[2];   // same-address broadcast
    const int lane = t & 63;
    const int wslot = h * 8 + (t >> 6);        // global wave id within cloud

    for (int it = 1; it < NS; ++it) {
      const int par = it & 1;
      const unsigned long long utag = (unsigned long long)it;
      unsigned long long* slotp = slot + par * 32;
      float bd = -1.f;
      int bj = 0;
      // exact numpy-f32 distance: plain muls (asm blocks fma contraction),
      // (sx+sy)+sz, v_min_f32 update; argmax tracked inline (strict > keeps
      // lowest j = lowest global index within this thread's stride).
#pragma unroll
      for (int j = 0; j < PPT; ++j) {
        float dx = px[j] - cx, dy = py[j] - cy, dz = pz[j] - cz;
        float sx = dx * dx, sy = dy * dy, sz = dz * dz;
        asm volatile("" : "+v"(sx), "+v"(sy), "+v"(sz));
        float nd = fminf(dv[j], (sx + sy) + sz);
        dv[j] = nd;
        if (nd > bd) { bd = nd; bj = j; }
      }
      const int gidx = gbase + bj * THR + t;
      // tagged monotone key: bigger dist wins, tie -> lower idx (np.argmax)
      unsigned long long wkey =
          (utag << 48) |
          ((unsigned long long)(unsigned)__float_as_int(bd) << 15) |
          (unsigned)(32767 - gidx);
#pragma unroll
      for (int o = 32; o > 0; o >>= 1) {
        unsigned long long ok = __shfl_xor(wkey, o, 64);
        wkey = ok > wkey ? ok : wkey;
      }
      if (lane == 0)                           // wave winner -> its own slot
        __hip_atomic_store(&slotp[wslot], wkey,
                           __ATOMIC_RELAXED, __HIP_MEMORY_SCOPE_AGENT);
      // all waves poll all 32 wave-slots (lane l watches slot l&31)
      unsigned long long v;
      do {
        v = __hip_atomic_load(&slotp[lane & 31],
                              __ATOMIC_RELAXED, __HIP_MEMORY_SCOPE_AGENT);
      } while (!__all((int)((v >> 48) == utag)));
      // butterfly max-merge of the 32 slot values (halves identical)
#pragma unroll
      for (int o = 16; o > 0; o >>= 1) {
        unsigned long long ov = __shfl_xor(v, o, 64);
        v = ov > v ? ov : v;
      }
      const int widx = 32767 - (int)(v & 0x7fff);
      if (h == 0 && t == 0) idx_out[it] = widx;
      cx = xyz[widx * 3 + 0];                  // same-address broadcast load
      cy = xyz[widx * 3 + 1];
      cz = xyz[widx * 3 + 2];
    }
  } else {
    // non-FPS linear index: 16 fillers inside bid<32, rest from 32 up
    const int g = (bid < 32) ? ((bid >> 3) * 4 + (bid & 7) - 4) : (bid - 16);
    if (g < 128) {
      // ---------------- Gram partial: G += chunk^T chunk ----------------
      const float* fr = feat + (size_t)g * 1024 * CIN;
      const int ti = (t & 31) * 4;
      const int tj = (t >> 5) * 8;
      float acc[4][8];
#pragma unroll
      for (int a = 0; a < 4; ++a)
#pragma unroll
        for (int b2 = 0; b2 < 8; ++b2) acc[a][b2] = 0.f;
#pragma unroll 4
      for (int r = 0; r < 1024; ++r) {
        const float* rowp = fr + r * CIN;
        float4 a4 = *(const float4*)(rowp + ti);
        float4 b4 = *(const float4*)(rowp + tj);
        float4 b5 = *(const float4*)(rowp + tj + 4);
        float av[4] = {a4.x, a4.y, a4.z, a4.w};
        float bv[8] = {b4.x, b4.y, b4.z, b4.w, b5.x, b5.y, b5.z, b5.w};
#pragma unroll
        for (int a = 0; a < 4; ++a)
#pragma unroll
          for (int b2 = 0; b2 < 8; ++b2) acc[a][b2] += av[a] * bv[b2];
      }
      float* G = wsf + WS_G;
#pragma unroll
      for (int a = 0; a < 4; ++a)
#pragma unroll
        for (int b2 = 0; b2 < 8; ++b2)
          atomicAdd(&G[(ti + a) * CIN + (tj + b2)], acc[a][b2]);
    } else {
      // ---------------- column sums of feat ----------------
      float (*s_fs)[128] = (float (*)[128])smem;
      const int fb = g - 128;             // 0..7
      const size_t base = (size_t)fb * 16384;
      const int c = t & 127, rg = t >> 7; // 0..3
      float s = 0.f;
      for (int r = rg; r < 16384; r += 4)
        s += feat[(base + r) * CIN + c];
      s_fs[rg][c] = s;
      __syncthreads();
      if (t < 128) {
        float v = s_fs[0][t] + s_fs[1][t] + s_fs[2][t] + s_fs[3][t];
        atomicAdd(&wsf[WS_FSUM + t], v);
      }
    }
  }
}

// mean[c] = (fsum . W[c]) / M ; E[x^2][c] = W[c]^T G W[c] / M
__global__ __launch_bounds__(128) void finalize_k(
    const float* __restrict__ W, const float* __restrict__ gamma,
    const float* __restrict__ beta, float* __restrict__ wsf)
{
  const int c = blockIdx.x, i = threadIdx.x;
  const float* G = wsf + WS_G;
  const float* fsum = wsf + WS_FSUM;
  const float* Gi = G + i * CIN;
  const float* Wc = W + c * CIN;
  float td = 0.f;
#pragma unroll 8
  for (int j = 0; j < CIN; j += 4) {
    float4 g4 = *(const float4*)(Gi + j);
    float4 w4 = *(const float4*)(Wc + j);
    td += g4.x * w4.x + g4.y * w4.y + g4.z * w4.z + g4.w * w4.w;
  }
  const float wci = Wc[i];
  float q = wci * td;
  float m = fsum[i] * wci;
#pragma unroll
  for (int o = 32; o > 0; o >>= 1) {
    q += __shfl_xor(q, o, 64);
    m += __shfl_xor(m, o, 64);
  }
  __shared__ float sq[2], sm[2];
  if ((i & 63) == 0) { sq[i >> 6] = q; sm[i >> 6] = m; }
  __syncthreads();
  if (i == 0) {
    const float inv_m = 1.f / 131072.f;
    float mean = (sm[0] + sm[1]) * inv_m;
    float e2 = (sq[0] + sq[1]) * inv_m;
    float var = e2 - mean * mean;
    float rstd = rsqrtf(var + 1e-5f);
    float gs = gamma[c] * rstd;
    wsf[WS_GSCALE + c] = gs;
    wsf[WS_GBIAS + c] = beta[c] - mean * gs;
  }
}

// recompute x rows only at sampled indices, normalize + relu, gather coords
__global__ __launch_bounds__(256) void gather_k(
    const float* __restrict__ coord, const float* __restrict__ feat,
    const float* __restrict__ W, const float* __restrict__ wsf,
    const int* __restrict__ wsi, float* __restrict__ out)
{
  const int p = blockIdx.x, t = threadIdx.x;
  const int b = p >> 11;
  const int idx = wsi[p];
  const size_t row = (size_t)b * NPT + idx;
  __shared__ float lf[CIN];
  if (t < CIN) lf[t] = feat[row * CIN + t];
  __syncthreads();
  const float* Wc = W + t * CIN;
  float acc = 0.f;
#pragma unroll 8
  for (int k = 0; k < CIN; k += 4) {
    float4 w4 = *(const float4*)(Wc + k);
    acc += lf[k] * w4.x + lf[k + 1] * w4.y + lf[k + 2] * w4.z + lf[k + 3] * w4.w;
  }
  float y = fmaxf(fmaf(acc, wsf[WS_GSCALE + t], wsf[WS_GBIAS + t]), 0.f);
  out[OUT_FEAT + (size_t)p * COUT + t] = y;
  if (t < 3) out[OUT_COORD + p * 3 + t] = coord[row * 3 + t];
  if (p == 0 && t < 4) out[OUT_OFFS + t] = (float)((t + 1) * NS);
}

extern "C" void kernel_launch(void* const* d_in, const int* in_sizes, int n_in,
                              void* d_out, int out_size, void* d_ws, size_t ws_size,
                              hipStream_t stream)
{
  const float* coord = (const float*)d_in[0];
  const float* feat  = (const float*)d_in[1];
  // d_in[2] = offset (implied by constants)
  const float* W     = (const float*)d_in[3];
  const float* gamma = (const float*)d_in[4];
  const float* beta  = (const float*)d_in[5];
  float* wsf = (float*)d_ws;
  int* wsi = (int*)(wsf + WS_IDX);
  unsigned long long* slots = (unsigned long long*)(wsf + WS_SLOT);
  float* out = (float*)d_out;

  // zero Gram + colsum accumulators AND all wave-slots (kills stale tags
  // across graph replays; stream-ordered before fused1)
  hipMemsetAsync(d_ws, 0, (WS_SLOT + 512) * sizeof(float), stream);

  fused1<<<152, THR, 0, stream>>>(coord, feat, wsf, wsi, slots);
  finalize_k<<<COUT, 128, 0, stream>>>(W, gamma, beta, wsf);
  gather_k<<<NB * NS, 256, 0, stream>>>(coord, feat, W, wsf, wsi, out);
}

// Round 11
// 6060.073 us; speedup vs baseline: 1.2617x; 1.2617x over previous
//
#include <hip/hip_runtime.h>

#define NB 4
#define NPT 32768
#define QPT 8192          // points per quarter-cloud
#define CIN 128
#define COUT 256
#define NS 2048
#define THR 512
#define PPT 16            // points per thread (QPT / THR)

// ws float-offset layout
#define WS_G 0            // 128*128 Gram
#define WS_FSUM 16384     // 128 column sums
#define WS_SLOT 16512     // 4 clouds x 32 u64 (256B padded) = 256 floats
#define WS_GSCALE 16768   // 256
#define WS_GBIAS 17024    // 256
#define WS_IDX 17280      // 8192 ints

// d_out float-offset layout
#define OUT_COORD 0
#define OUT_FEAT 24576
#define OUT_OFFS 2121728

// Established rounds 1-10:
//  * The compiler NEVER keeps the per-thread coord arrays in VGPRs
//    (VGPR_Count 48-76 across all variants, vs 64+ needed) -- px/py/pz were
//    re-loaded from L2 every iteration (~96 KB/CU/iter, ~1500 cyc serial).
//    No launch_bounds / amdgpu attr / LDS-size knob changes this. Fix:
//    coords live in LDS explicitly (96 KB: float2 xy + float z per point;
//    160 KB/CU available, r5 proved >64 KB static works). dv[16] stays in
//    registers (proven register-resident; no scratch traffic).
//  * WRITE_SIZE ~66 MB = Gram's memory-side atomics; expected, harmless.
//  * agent-scope atomics are memory-side (~600-900 cyc RT); rocprof
//    inflates spin-poll kernels -- compare unprofiled totals only.
//  * r10's 32-slot no-barrier exchange regressed (slowest-of-32 gating);
//    r8's structure is best: wave butterfly -> LDS atomicMax -> ONE barrier
//    -> unique winner stores tagged key -> all threads poll the 4 slots.
//  * tagged monotone key it<<48 | dbits<<15 | (32767-gidx): stale values
//    lose atomicMax automatically; slot reuse at parity distance 2 is safe
//    (store(it+2) happens-after this block passed poll(it+1), which
//    requires every block's store(it+1), which is post-B0(it+1), i.e.
//    after all its waves consumed iter it).
//  * NEW: pad each cloud's slots to 256 B (r8 packed 2 clouds/128B line ->
//    cross-XCD false sharing on the poll path).
__global__ __launch_bounds__(THR) void fused1(
    const float* __restrict__ coord, const float* __restrict__ feat,
    float* __restrict__ wsf, int* __restrict__ wsi,
    unsigned long long* __restrict__ slots)
{
  __shared__ float2 lxy[QPT];                 // 65536 B
  __shared__ float lz[QPT];                   // 32768 B
  __shared__ unsigned long long s_key[2];
  __shared__ float s_fs[4][128];              // colsum scratch (2 KB)

  const int bid = blockIdx.x;
  const int t = threadIdx.x;
  const bool is_fps = (bid < 32) && ((bid & 7) < 4);

  if (is_fps) {
    // ---------------- FPS: cloud cl, quarter h ----------------
    const int cl = bid & 3;
    const int h = bid >> 3;            // 0..3; bids {cl,cl+8,cl+16,cl+24} -> one XCD
    const int gbase = h * QPT;
    const float* xyz = coord + (size_t)cl * NPT * 3;
    int* idx_out = wsi + cl * NS;
    unsigned long long* slot = slots + cl * 32;   // 256B-padded per cloud

    float dv[PPT];
#pragma unroll
    for (int j = 0; j < PPT; ++j) {
      const int l = j * THR + t;
      const int p = gbase + l;
      lxy[l] = make_float2(xyz[p * 3 + 0], xyz[p * 3 + 1]);
      lz[l] = xyz[p * 3 + 2];
      dv[j] = 1e10f;
    }
    if (t == 0) {
      if (h == 0) idx_out[0] = 0;      // every cloud writes sample 0
      s_key[0] = s_key[1] = 0ull;      // tag 0 < any it>=1
    }
    float cx = xyz[0], cy = xyz[1], cz = xyz[2];   // same-address broadcast
    __syncthreads();                   // LDS coords + s_key ready

    const int lane = t & 63;
    for (int it = 1; it < NS; ++it) {
      const int par = it & 1;
      const unsigned long long utag = (unsigned long long)it;
      float bd = -1.f;
      int bj = 0;
      // exact numpy-f32 distance: plain muls (asm blocks fma contraction),
      // (sx+sy)+sz, v_min_f32 update; argmax tracked inline (strict > keeps
      // lowest j = lowest global index within this thread's stride).
      // Coords from LDS (stride-1 per wave: conflict-free).
#pragma unroll
      for (int j = 0; j < PPT; ++j) {
        const int l = j * THR + t;
        const float2 xy = lxy[l];
        const float zz = lz[l];
        float dx = xy.x - cx, dy = xy.y - cy, dz = zz - cz;
        float sx = dx * dx, sy = dy * dy, sz = dz * dz;
        asm volatile("" : "+v"(sx), "+v"(sy), "+v"(sz));
        float nd = fminf(dv[j], (sx + sy) + sz);
        dv[j] = nd;
        if (nd > bd) { bd = nd; bj = j; }
      }
      const int gidx = gbase + bj * THR + t;
      // tagged monotone key: bigger dist wins, tie -> lower idx (np.argmax)
      const unsigned long long tkey =
          (utag << 48) |
          ((unsigned long long)(unsigned)__float_as_int(bd) << 15) |
          (unsigned)(32767 - gidx);
      unsigned long long wkey = tkey;
#pragma unroll
      for (int o = 32; o > 0; o >>= 1) {
        unsigned long long ok = __shfl_xor(wkey, o, 64);
        wkey = ok > wkey ? ok : wkey;
      }
      if (lane == 0) atomicMax(&s_key[par], wkey);
      __syncthreads();                 // the ONLY barrier per iter
      const unsigned long long skey = s_key[par];
      if (tkey == skey)                // unique winner thread (gidx unique)
        __hip_atomic_store(&slot[par * 4 + h], skey,
                           __ATOMIC_RELAXED, __HIP_MEMORY_SCOPE_AGENT);
      unsigned long long v0, v1, v2, v3;
      do {                             // all threads poll, wave-uniform
        v0 = __hip_atomic_load(&slot[par * 4 + 0],
                               __ATOMIC_RELAXED, __HIP_MEMORY_SCOPE_AGENT);
        v1 = __hip_atomic_load(&slot[par * 4 + 1],
                               __ATOMIC_RELAXED, __HIP_MEMORY_SCOPE_AGENT);
        v2 = __hip_atomic_load(&slot[par * 4 + 2],
                               __ATOMIC_RELAXED, __HIP_MEMORY_SCOPE_AGENT);
        v3 = __hip_atomic_load(&slot[par * 4 + 3],
                               __ATOMIC_RELAXED, __HIP_MEMORY_SCOPE_AGENT);
      } while ((v0 >> 48) != utag || (v1 >> 48) != utag ||
               (v2 >> 48) != utag || (v3 >> 48) != utag);
      const unsigned long long b01 = v0 > v1 ? v0 : v1;
      const unsigned long long b23 = v2 > v3 ? v2 : v3;
      const unsigned long long best = b01 > b23 ? b01 : b23;
      const int widx = 32767 - (int)(best & 0x7fff);
      if (h == 0 && t == 0) idx_out[it] = widx;
      cx = xyz[widx * 3 + 0];          // same-address broadcast load (L2)
      cy = xyz[widx * 3 + 1];
      cz = xyz[widx * 3 + 2];
    }
  } else {
    // non-FPS linear index: 16 fillers inside bid<32, rest from 32 up
    const int g = (bid < 32) ? ((bid >> 3) * 4 + (bid & 7) - 4) : (bid - 16);
    if (g < 128) {
      // ---------------- Gram partial: G += chunk^T chunk ----------------
      const float* fr = feat + (size_t)g * 1024 * CIN;
      const int ti = (t & 31) * 4;
      const int tj = (t >> 5) * 8;
      float acc[4][8];
#pragma unroll
      for (int a = 0; a < 4; ++a)
#pragma unroll
        for (int b2 = 0; b2 < 8; ++b2) acc[a][b2] = 0.f;
#pragma unroll 4
      for (int r = 0; r < 1024; ++r) {
        const float* rowp = fr + r * CIN;
        float4 a4 = *(const float4*)(rowp + ti);
        float4 b4 = *(const float4*)(rowp + tj);
        float4 b5 = *(const float4*)(rowp + tj + 4);
        float av[4] = {a4.x, a4.y, a4.z, a4.w};
        float bv[8] = {b4.x, b4.y, b4.z, b4.w, b5.x, b5.y, b5.z, b5.w};
#pragma unroll
        for (int a = 0; a < 4; ++a)
#pragma unroll
          for (int b2 = 0; b2 < 8; ++b2) acc[a][b2] += av[a] * bv[b2];
      }
      float* G = wsf + WS_G;
#pragma unroll
      for (int a = 0; a < 4; ++a)
#pragma unroll
        for (int b2 = 0; b2 < 8; ++b2)
          atomicAdd(&G[(ti + a) * CIN + (tj + b2)], acc[a][b2]);
    } else {
      // ---------------- column sums of feat ----------------
      const int fb = g - 128;             // 0..7
      const size_t base = (size_t)fb * 16384;
      const int c = t & 127, rg = t >> 7; // 0..3
      float s = 0.f;
      for (int r = rg; r < 16384; r += 4)
        s += feat[(base + r) * CIN + c];
      s_fs[rg][c] = s;
      __syncthreads();
      if (t < 128) {
        float v = s_fs[0][t] + s_fs[1][t] + s_fs[2][t] + s_fs[3][t];
        atomicAdd(&wsf[WS_FSUM + t], v);
      }
    }
  }
}

// mean[c] = (fsum . W[c]) / M ; E[x^2][c] = W[c]^T G W[c] / M
__global__ __launch_bounds__(128) void finalize_k(
    const float* __restrict__ W, const float* __restrict__ gamma,
    const float* __restrict__ beta, float* __restrict__ wsf)
{
  const int c = blockIdx.x, i = threadIdx.x;
  const float* G = wsf + WS_G;
  const float* fsum = wsf + WS_FSUM;
  const float* Gi = G + i * CIN;
  const float* Wc = W + c * CIN;
  float td = 0.f;
#pragma unroll 8
  for (int j = 0; j < CIN; j += 4) {
    float4 g4 = *(const float4*)(Gi + j);
    float4 w4 = *(const float4*)(Wc + j);
    td += g4.x * w4.x + g4.y * w4.y + g4.z * w4.z + g4.w * w4.w;
  }
  const float wci = Wc[i];
  float q = wci * td;
  float m = fsum[i] * wci;
#pragma unroll
  for (int o = 32; o > 0; o >>= 1) {
    q += __shfl_xor(q, o, 64);
    m += __shfl_xor(m, o, 64);
  }
  __shared__ float sq[2], sm[2];
  if ((i & 63) == 0) { sq[i >> 6] = q; sm[i >> 6] = m; }
  __syncthreads();
  if (i == 0) {
    const float inv_m = 1.f / 131072.f;
    float mean = (sm[0] + sm[1]) * inv_m;
    float e2 = (sq[0] + sq[1]) * inv_m;
    float var = e2 - mean * mean;
    float rstd = rsqrtf(var + 1e-5f);
    float gs = gamma[c] * rstd;
    wsf[WS_GSCALE + c] = gs;
    wsf[WS_GBIAS + c] = beta[c] - mean * gs;
  }
}

// recompute x rows only at sampled indices, normalize + relu, gather coords
__global__ __launch_bounds__(256) void gather_k(
    const float* __restrict__ coord, const float* __restrict__ feat,
    const float* __restrict__ W, const float* __restrict__ wsf,
    const int* __restrict__ wsi, float* __restrict__ out)
{
  const int p = blockIdx.x, t = threadIdx.x;
  const int b = p >> 11;
  const int idx = wsi[p];
  const size_t row = (size_t)b * NPT + idx;
  __shared__ float lf[CIN];
  if (t < CIN) lf[t] = feat[row * CIN + t];
  __syncthreads();
  const float* Wc = W + t * CIN;
  float acc = 0.f;
#pragma unroll 8
  for (int k = 0; k < CIN; k += 4) {
    float4 w4 = *(const float4*)(Wc + k);
    acc += lf[k] * w4.x + lf[k + 1] * w4.y + lf[k + 2] * w4.z + lf[k + 3] * w4.w;
  }
  float y = fmaxf(fmaf(acc, wsf[WS_GSCALE + t], wsf[WS_GBIAS + t]), 0.f);
  out[OUT_FEAT + (size_t)p * COUT + t] = y;
  if (t < 3) out[OUT_COORD + p * 3 + t] = coord[row * 3 + t];
  if (p == 0 && t < 4) out[OUT_OFFS + t] = (float)((t + 1) * NS);
}

extern "C" void kernel_launch(void* const* d_in, const int* in_sizes, int n_in,
                              void* d_out, int out_size, void* d_ws, size_t ws_size,
                              hipStream_t stream)
{
  const float* coord = (const float*)d_in[0];
  const float* feat  = (const float*)d_in[1];
  // d_in[2] = offset (implied by constants)
  const float* W     = (const float*)d_in[3];
  const float* gamma = (const float*)d_in[4];
  const float* beta  = (const float*)d_in[5];
  float* wsf = (float*)d_ws;
  int* wsi = (int*)(wsf + WS_IDX);
  unsigned long long* slots = (unsigned long long*)(wsf + WS_SLOT);
  float* out = (float*)d_out;

  // zero Gram + colsum accumulators AND all sync slots (kills stale tags
  // across graph replays; stream-ordered before fused1)
  hipMemsetAsync(d_ws, 0, (WS_SLOT + 256) * sizeof(float), stream);

  fused1<<<152, THR, 0, stream>>>(coord, feat, wsf, wsi, slots);
  finalize_k<<<COUT, 128, 0, stream>>>(W, gamma, beta, wsf);
  gather_k<<<NB * NS, 256, 0, stream>>>(coord, feat, W, wsf, wsi, out);
}

// Round 12
// 4416.225 us; speedup vs baseline: 1.7313x; 1.3722x over previous
//
#include <hip/hip_runtime.h>

#define NB 4
#define NPT 32768
#define QPT 8192          // points per quarter-cloud
#define CIN 128
#define COUT 256
#define NS 2048
#define THR 512
#define PPT 16            // points per thread (QPT / THR)

// ws float-offset layout
#define WS_G 0            // 128*128 Gram
#define WS_FSUM 16384     // 128 column sums
#define WS_SLOT 16512     // 4 clouds x 32 u64 (256B padded) = 256 floats
#define WS_GSCALE 16768   // 256
#define WS_GBIAS 17024    // 256
#define WS_IDX 17280      // 8192 ints

// d_out float-offset layout
#define OUT_COORD 0
#define OUT_FEAT 24576
#define OUT_OFFS 2121728

// Established rounds 1-11:
//  * Compute path is NOT the bottleneck (r7/r9/r11 compute changes ~0):
//    with ~20 active CUs, L2 is idle; coord reloads pipeline for free.
//  * The ~2.2 us/iter floor is the cross-block EXCHANGE; r8<r9<r10 ordering
//    implicates same-address poll flooding: every thread polling the same
//    fine-grained slots -> wave atomic loads likely serialize per-lane at
//    the memory-side atomic unit; winner's store queues behind them.
//  * THIS ROUND (one change vs r11): per wave only lanes 0-3 poll (one
//    32B request/wave/round, s_sleep backoff). 8192 -> 32 pollers/cloud.
//  * Coords in LDS (96 KB), dv[16] in regs; WRITE ~66 MB = Gram atomics
//    (expected); rocprof inflates spin kernels -> compare unprofiled totals.
//  * Tagged monotone key it<<48 | dbits<<15 | (32767-gidx): stale slot
//    values lose atomicMax automatically; slot reuse at parity distance 2
//    safe (store(it+2) happens-after passing poll(it+1) which requires all
//    blocks' store(it+1), post-B0(it+1), after all waves consumed it).
__global__ __launch_bounds__(THR) void fused1(
    const float* __restrict__ coord, const float* __restrict__ feat,
    float* __restrict__ wsf, int* __restrict__ wsi,
    unsigned long long* __restrict__ slots)
{
  __shared__ float2 lxy[QPT];                 // 65536 B
  __shared__ float lz[QPT];                   // 32768 B
  __shared__ unsigned long long s_key[2];
  __shared__ float s_fs[4][128];              // colsum scratch (2 KB)

  const int bid = blockIdx.x;
  const int t = threadIdx.x;
  const bool is_fps = (bid < 32) && ((bid & 7) < 4);

  if (is_fps) {
    // ---------------- FPS: cloud cl, quarter h ----------------
    const int cl = bid & 3;
    const int h = bid >> 3;            // 0..3; bids {cl,cl+8,cl+16,cl+24} -> one XCD
    const int gbase = h * QPT;
    const float* xyz = coord + (size_t)cl * NPT * 3;
    int* idx_out = wsi + cl * NS;
    unsigned long long* slot = slots + cl * 32;   // 256B-padded per cloud

    float dv[PPT];
#pragma unroll
    for (int j = 0; j < PPT; ++j) {
      const int l = j * THR + t;
      const int p = gbase + l;
      lxy[l] = make_float2(xyz[p * 3 + 0], xyz[p * 3 + 1]);
      lz[l] = xyz[p * 3 + 2];
      dv[j] = 1e10f;
    }
    if (t == 0) {
      if (h == 0) idx_out[0] = 0;      // every cloud writes sample 0
      s_key[0] = s_key[1] = 0ull;      // tag 0 < any it>=1
    }
    float cx = xyz[0], cy = xyz[1], cz = xyz[2];   // same-address broadcast
    __syncthreads();                   // LDS coords + s_key ready

    const int lane = t & 63;
    for (int it = 1; it < NS; ++it) {
      const int par = it & 1;
      const unsigned long long utag = (unsigned long long)it;
      float bd = -1.f;
      int bj = 0;
      // exact numpy-f32 distance: plain muls (asm blocks fma contraction),
      // (sx+sy)+sz, v_min_f32 update; argmax tracked inline (strict > keeps
      // lowest j = lowest global index within this thread's stride).
#pragma unroll
      for (int j = 0; j < PPT; ++j) {
        const int l = j * THR + t;
        const float2 xy = lxy[l];
        const float zz = lz[l];
        float dx = xy.x - cx, dy = xy.y - cy, dz = zz - cz;
        float sx = dx * dx, sy = dy * dy, sz = dz * dz;
        asm volatile("" : "+v"(sx), "+v"(sy), "+v"(sz));
        float nd = fminf(dv[j], (sx + sy) + sz);
        dv[j] = nd;
        if (nd > bd) { bd = nd; bj = j; }
      }
      const int gidx = gbase + bj * THR + t;
      // tagged monotone key: bigger dist wins, tie -> lower idx (np.argmax)
      const unsigned long long tkey =
          (utag << 48) |
          ((unsigned long long)(unsigned)__float_as_int(bd) << 15) |
          (unsigned)(32767 - gidx);
      unsigned long long wkey = tkey;
#pragma unroll
      for (int o = 32; o > 0; o >>= 1) {
        unsigned long long ok = __shfl_xor(wkey, o, 64);
        wkey = ok > wkey ? ok : wkey;
      }
      if (lane == 0) atomicMax(&s_key[par], wkey);
      __syncthreads();                 // the ONLY barrier per iter
      const unsigned long long skey = s_key[par];
      if (tkey == skey)                // unique winner thread (gidx unique)
        __hip_atomic_store(&slot[par * 4 + h], skey,
                           __ATOMIC_RELAXED, __HIP_MEMORY_SCOPE_AGENT);
      // poll: lanes 0-3 only -> ONE 32B request per wave per round
      unsigned long long v = 0;
      for (;;) {
        if (lane < 4)
          v = __hip_atomic_load(&slot[par * 4 + lane],
                                __ATOMIC_RELAXED, __HIP_MEMORY_SCOPE_AGENT);
        const bool ok = (lane >= 4) || ((v >> 48) == utag);
        if (__all((int)ok)) break;
        __builtin_amdgcn_s_sleep(1);   // thin the retry traffic
      }
      unsigned long long o1 = __shfl_xor(v, 1, 64);
      v = o1 > v ? o1 : v;
      unsigned long long o2 = __shfl_xor(v, 2, 64);
      v = o2 > v ? o2 : v;
      v = __shfl(v, 0, 64);            // broadcast merged winner to all lanes
      const int widx = 32767 - (int)(v & 0x7fff);
      if (h == 0 && t == 0) idx_out[it] = widx;
      cx = xyz[widx * 3 + 0];          // same-address broadcast load (L2)
      cy = xyz[widx * 3 + 1];
      cz = xyz[widx * 3 + 2];
    }
  } else {
    // non-FPS linear index: 16 fillers inside bid<32, rest from 32 up
    const int g = (bid < 32) ? ((bid >> 3) * 4 + (bid & 7) - 4) : (bid - 16);
    if (g < 128) {
      // ---------------- Gram partial: G += chunk^T chunk ----------------
      const float* fr = feat + (size_t)g * 1024 * CIN;
      const int ti = (t & 31) * 4;
      const int tj = (t >> 5) * 8;
      float acc[4][8];
#pragma unroll
      for (int a = 0; a < 4; ++a)
#pragma unroll
        for (int b2 = 0; b2 < 8; ++b2) acc[a][b2] = 0.f;
#pragma unroll 4
      for (int r = 0; r < 1024; ++r) {
        const float* rowp = fr + r * CIN;
        float4 a4 = *(const float4*)(rowp + ti);
        float4 b4 = *(const float4*)(rowp + tj);
        float4 b5 = *(const float4*)(rowp + tj + 4);
        float av[4] = {a4.x, a4.y, a4.z, a4.w};
        float bv[8] = {b4.x, b4.y, b4.z, b4.w, b5.x, b5.y, b5.z, b5.w};
#pragma unroll
        for (int a = 0; a < 4; ++a)
#pragma unroll
          for (int b2 = 0; b2 < 8; ++b2) acc[a][b2] += av[a] * bv[b2];
      }
      float* G = wsf + WS_G;
#pragma unroll
      for (int a = 0; a < 4; ++a)
#pragma unroll
        for (int b2 = 0; b2 < 8; ++b2)
          atomicAdd(&G[(ti + a) * CIN + (tj + b2)], acc[a][b2]);
    } else {
      // ---------------- column sums of feat ----------------
      const int fb = g - 128;             // 0..7
      const size_t base = (size_t)fb * 16384;
      const int c = t & 127, rg = t >> 7; // 0..3
      float s = 0.f;
      for (int r = rg; r < 16384; r += 4)
        s += feat[(base + r) * CIN + c];
      s_fs[rg][c] = s;
      __syncthreads();
      if (t < 128) {
        float v = s_fs[0][t] + s_fs[1][t] + s_fs[2][t] + s_fs[3][t];
        atomicAdd(&wsf[WS_FSUM + t], v);
      }
    }
  }
}

// mean[c] = (fsum . W[c]) / M ; E[x^2][c] = W[c]^T G W[c] / M
__global__ __launch_bounds__(128) void finalize_k(
    const float* __restrict__ W, const float* __restrict__ gamma,
    const float* __restrict__ beta, float* __restrict__ wsf)
{
  const int c = blockIdx.x, i = threadIdx.x;
  const float* G = wsf + WS_G;
  const float* fsum = wsf + WS_FSUM;
  const float* Gi = G + i * CIN;
  const float* Wc = W + c * CIN;
  float td = 0.f;
#pragma unroll 8
  for (int j = 0; j < CIN; j += 4) {
    float4 g4 = *(const float4*)(Gi + j);
    float4 w4 = *(const float4*)(Wc + j);
    td += g4.x * w4.x + g4.y * w4.y + g4.z * w4.z + g4.w * w4.w;
  }
  const float wci = Wc[i];
  float q = wci * td;
  float m = fsum[i] * wci;
#pragma unroll
  for (int o = 32; o > 0; o >>= 1) {
    q += __shfl_xor(q, o, 64);
    m += __shfl_xor(m, o, 64);
  }
  __shared__ float sq[2], sm[2];
  if ((i & 63) == 0) { sq[i >> 6] = q; sm[i >> 6] = m; }
  __syncthreads();
  if (i == 0) {
    const float inv_m = 1.f / 131072.f;
    float mean = (sm[0] + sm[1]) * inv_m;
    float e2 = (sq[0] + sq[1]) * inv_m;
    float var = e2 - mean * mean;
    float rstd = rsqrtf(var + 1e-5f);
    float gs = gamma[c] * rstd;
    wsf[WS_GSCALE + c] = gs;
    wsf[WS_GBIAS + c] = beta[c] - mean * gs;
  }
}

// recompute x rows only at sampled indices, normalize + relu, gather coords
__global__ __launch_bounds__(256) void gather_k(
    const float* __restrict__ coord, const float* __restrict__ feat,
    const float* __restrict__ W, const float* __restrict__ wsf,
    const int* __restrict__ wsi, float* __restrict__ out)
{
  const int p = blockIdx.x, t = threadIdx.x;
  const int b = p >> 11;
  const int idx = wsi[p];
  const size_t row = (size_t)b * NPT + idx;
  __shared__ float lf[CIN];
  if (t < CIN) lf[t] = feat[row * CIN + t];
  __syncthreads();
  const float* Wc = W + t * CIN;
  float acc = 0.f;
#pragma unroll 8
  for (int k = 0; k < CIN; k += 4) {
    float4 w4 = *(const float4*)(Wc + k);
    acc += lf[k] * w4.x + lf[k + 1] * w4.y + lf[k + 2] * w4.z + lf[k + 3] * w4.w;
  }
  float y = fmaxf(fmaf(acc, wsf[WS_GSCALE + t], wsf[WS_GBIAS + t]), 0.f);
  out[OUT_FEAT + (size_t)p * COUT + t] = y;
  if (t < 3) out[OUT_COORD + p * 3 + t] = coord[row * 3 + t];
  if (p == 0 && t < 4) out[OUT_OFFS + t] = (float)((t + 1) * NS);
}

extern "C" void kernel_launch(void* const* d_in, const int* in_sizes, int n_in,
                              void* d_out, int out_size, void* d_ws, size_t ws_size,
                              hipStream_t stream)
{
  const float* coord = (const float*)d_in[0];
  const float* feat  = (const float*)d_in[1];
  // d_in[2] = offset (implied by constants)
  const float* W     = (const float*)d_in[3];
  const float* gamma = (const float*)d_in[4];
  const float* beta  = (const float*)d_in[5];
  float* wsf = (float*)d_ws;
  int* wsi = (int*)(wsf + WS_IDX);
  unsigned long long* slots = (unsigned long long*)(wsf + WS_SLOT);
  float* out = (float*)d_out;

  // zero Gram + colsum accumulators AND all sync slots (kills stale tags
  // across graph replays; stream-ordered before fused1)
  hipMemsetAsync(d_ws, 0, (WS_SLOT + 256) * sizeof(float), stream);

  fused1<<<152, THR, 0, stream>>>(coord, feat, wsf, wsi, slots);
  finalize_k<<<COUT, 128, 0, stream>>>(W, gamma, beta, wsf);
  gather_k<<<NB * NS, 256, 0, stream>>>(coord, feat, W, wsf, wsi, out);
}